// Round 5
// baseline (5297.662 us; speedup 1.0000x reference)
//
#include <hip/hip_runtime.h>
#include <hip/hip_bf16.h>
#include <stdint.h>

#define S_LEN 512
#define BATCH 64
#define DDIM  512
#define HID   512
#define SB    32768   // S_LEN*BATCH

typedef __attribute__((ext_vector_type(8))) short bf16x8;
typedef __attribute__((ext_vector_type(4))) float f32x4;

__device__ __forceinline__ float bf2f(short s) {
  return __uint_as_float(((unsigned)(unsigned short)s) << 16);
}

__device__ __forceinline__ void gload_lds16(const void* g, void* l) {
  __builtin_amdgcn_global_load_lds(
      (const __attribute__((address_space(1))) void*)g,
      (__attribute__((address_space(3))) void*)l, 16, 0, 0);
}

// ---------- prep kernels ----------

__global__ void k_f32_to_bf16(const float* __restrict__ src,
                              __hip_bfloat16* __restrict__ dst, int n) {
  int i = (blockIdx.x * blockDim.x + threadIdx.x) * 8;
  if (i >= n) return;
  float4 a = *(const float4*)(src + i);
  float4 b = *(const float4*)(src + i + 4);
  __hip_bfloat16 t[8];
  t[0] = __float2bfloat16(a.x); t[1] = __float2bfloat16(a.y);
  t[2] = __float2bfloat16(a.z); t[3] = __float2bfloat16(a.w);
  t[4] = __float2bfloat16(b.x); t[5] = __float2bfloat16(b.y);
  t[6] = __float2bfloat16(b.z); t[7] = __float2bfloat16(b.w);
  *(bf16x8*)(dst + i) = *(bf16x8*)t;
}

__global__ void k_permW(const float* __restrict__ src,
                        __hip_bfloat16* __restrict__ dst, int K) {
  int idx = blockIdx.x * 256 + threadIdx.x;
  int p = idx / K, k = idx - p * K;
  int g = p & 3, j = p >> 2;
  dst[idx] = __float2bfloat16(src[(size_t)(g * HID + j) * K + k]);
}

__global__ void k_permB(const float* __restrict__ bih, const float* __restrict__ bhh,
                        float* __restrict__ dst) {
  int p = blockIdx.x * 256 + threadIdx.x;
  int g = p & 3, j = p >> 2;
  dst[p] = bih[g * HID + j] + bhh[g * HID + j];
}

// ---------- input-projection GEMM (unchanged, proven) ----------
__global__ __launch_bounds__(256) void k_gemm_in(
    const __hip_bfloat16* __restrict__ A,
    const __hip_bfloat16* __restrict__ W,
    const float* __restrict__ bsumL,
    __hip_bfloat16* __restrict__ G,
    int K) {
  __shared__ uint4 lds4[2048];
  char* ldsA = (char*)lds4;
  char* ldsB = (char*)lds4 + 16384;
  int tid = threadIdx.x, lane = tid & 63, wid = tid >> 6;
  int wm = wid >> 1, wn = wid & 1;
  int bm = blockIdx.x, by = blockIdx.y;
  int lr = lane & 15, lk = lane >> 4;
  f32x4 acc[4][4] = {};
  const char* gA = (const char*)A;
  const char* gW = (const char*)W;
  for (int kk = 0; kk < K; kk += 64) {
    #pragma unroll
    for (int i = 0; i < 4; i++) {
      int ch = i * 256 + tid;
      int row = ch >> 3, c16 = ch & 7;
      gload_lds16(gA + (size_t)(bm * 128 + row) * (K * 2) + kk * 2 + c16 * 16,
                  ldsA + (i * 256 + wid * 64) * 16);
      gload_lds16(gW + (size_t)(by * 128 + row) * (K * 2) + kk * 2 + c16 * 16,
                  ldsB + (i * 256 + wid * 64) * 16);
    }
    __syncthreads();
    #pragma unroll
    for (int ks = 0; ks < 2; ks++) {
      bf16x8 af[4], bfr[4];
      #pragma unroll
      for (int mi = 0; mi < 4; mi++) {
        int r = wm * 64 + mi * 16 + lr;
        af[mi] = *(const bf16x8*)(ldsA + r * 128 + ks * 64 + lk * 16);
      }
      #pragma unroll
      for (int ni = 0; ni < 4; ni++) {
        int r = wn * 64 + ni * 16 + lr;
        bfr[ni] = *(const bf16x8*)(ldsB + r * 128 + ks * 64 + lk * 16);
      }
      #pragma unroll
      for (int mi = 0; mi < 4; mi++)
        #pragma unroll
        for (int ni = 0; ni < 4; ni++)
          acc[mi][ni] = __builtin_amdgcn_mfma_f32_16x16x32_bf16(
              af[mi], bfr[ni], acc[mi][ni], 0, 0, 0);
    }
    __syncthreads();
  }
  #pragma unroll
  for (int ni = 0; ni < 4; ni++) {
    int n = by * 128 + wn * 64 + ni * 16 + lr;
    int d = n >> 11, p = n & 2047;
    float bias = bsumL[d * 2048 + p];
    #pragma unroll
    for (int mi = 0; mi < 4; mi++) {
      int mbase = bm * 128 + wm * 64 + mi * 16 + lk * 4;
      #pragma unroll
      for (int r = 0; r < 4; r++) {
        int m = mbase + r;
        G[((size_t)d * SB + m) * 2048 + p] =
            __float2bfloat16(acc[mi][ni][r] + bias);
      }
    }
  }
}

// ---------- persistent scan kernel, proxy-poll sentinel sync ----------
// 64 blocks (bn 0..31 col-tiles, dir 0..1) x 512 threads. Y is step-indexed,
// sentinel-prefilled (0xFFFF bf16 NaN). Each consumer thread's 16 words come
// from ONE producer block (c8 = tid&127 is load-index-invariant), so a single
// 8B proxy word gates readiness; bulk 64KB load happens exactly once.
__global__ __launch_bounds__(512, 1) void k_scan(
    const __hip_bfloat16* __restrict__ G,    // [2][SB][2048]
    const __hip_bfloat16* __restrict__ Whp,  // [2][2048][512] this layer
    __hip_bfloat16* __restrict__ Y,          // [SB][1024], sentinel-filled
    const float* __restrict__ mask,          // [S][B]
    float* __restrict__ outH,                // f32 h out (layer1) or null
    float* __restrict__ hn, float* __restrict__ cn) {
  __shared__ char ldsH[65536];               // [64 rows][1024B], swizzled
  __shared__ float gatesF[64 * 68];
  int tid = threadIdx.x, lane = tid & 63, wid = tid >> 6;
  int bn = blockIdx.x & 31;
  int dir = blockIdx.x >> 5;
  int wm = wid >> 1, wn = wid & 1;
  int lr = lane & 15, lk = lane >> 4;
  int arow = wm * 16 + lr;
  const __hip_bfloat16* Gd = G + (size_t)dir * SB * 2048;

  int cb = tid >> 3, cup = tid & 7;

  // Whh B-fragments (register-resident for the whole scan)
  bf16x8 bfrag[16][2];
  {
    const __hip_bfloat16* w0 =
        Whp + (size_t)(dir * 2048 + bn * 64 + wn * 32 + lr) * 512;
    #pragma unroll
    for (int ni = 0; ni < 2; ni++)
      #pragma unroll
      for (int ks = 0; ks < 16; ks++)
        bfrag[ks][ni] = *(const bf16x8*)(w0 + (size_t)ni * 16 * 512 + ks * 32 + lk * 8);
  }

  float creg[2] = {0.f, 0.f};

  int t0 = dir ? (S_LEN - 1) : 0;
  bf16x8 gv = *(const bf16x8*)(Gd + ((size_t)t0 * 64 + cb) * 2048 + bn * 64 + cup * 8);
  float mreg = mask[t0 * 64 + cb];

  for (int s = 0; s < S_LEN; ++s) {
    int t = dir ? (S_LEN - 1 - s) : s;
    f32x4 acc[2] = {};
    if (s > 0) {
      int tprev = dir ? t + 1 : t - 1;
      const char* srcH = (const char*)Y + (size_t)tprev * 131072 + dir * 1024;
      // per-thread load address for word i: same c8, rows i*4 + tid>>7
      uint64_t tH[16];
      // 1) cheap proxy poll: ONE 8B word (4KB/block/round, 16x less fabric
      //    traffic than a full round) until non-sentinel
      {
        int g2 = 0;
        for (;;) {
          int ch = tid, row = ch >> 7, c8 = ch & 127;
          uint64_t pv = __hip_atomic_load(
              (const uint64_t*)(srcH + (size_t)row * 2048 + c8 * 8),
              __ATOMIC_RELAXED, __HIP_MEMORY_SCOPE_AGENT);
          if (((pv & 0xFFFFull) != 0xFFFFull) &&
              (((pv >> 32) & 0xFFFFull) != 0xFFFFull)) break;
          __builtin_amdgcn_s_sleep(1);
          if (++g2 > (1 << 13)) break;  // hang-proof bail
        }
      }
      // 2) bulk load once
      #pragma unroll
      for (int i = 0; i < 16; ++i) {
        int ch = i * 512 + tid, row = ch >> 7, c8 = ch & 127;
        tH[i] = __hip_atomic_load(
            (const uint64_t*)(srcH + (size_t)row * 2048 + c8 * 8),
            __ATOMIC_RELAXED, __HIP_MEMORY_SCOPE_AGENT);
      }
      // 3) verify; rare straggler path: proxy-poll first failing word, reload
      {
        int guard = 0;
        for (;;) {
          int fi = -1;
          #pragma unroll
          for (int i = 0; i < 16; ++i) {
            uint64_t v = tH[i];
            bool bad = ((v & 0xFFFFull) == 0xFFFFull) ||
                       (((v >> 32) & 0xFFFFull) == 0xFFFFull);
            if (bad && fi < 0) fi = i;
          }
          if (fi < 0) break;
          int ch = fi * 512 + tid, row = ch >> 7, c8 = ch & 127;
          int g2 = 0;
          for (;;) {
            uint64_t pv = __hip_atomic_load(
                (const uint64_t*)(srcH + (size_t)row * 2048 + c8 * 8),
                __ATOMIC_RELAXED, __HIP_MEMORY_SCOPE_AGENT);
            if (((pv & 0xFFFFull) != 0xFFFFull) &&
                (((pv >> 32) & 0xFFFFull) != 0xFFFFull)) break;
            __builtin_amdgcn_s_sleep(1);
            if (++g2 > (1 << 12)) break;
          }
          #pragma unroll
          for (int i = 0; i < 16; ++i) {
            int ch2 = i * 512 + tid, row2 = ch2 >> 7, c82 = ch2 & 127;
            tH[i] = __hip_atomic_load(
                (const uint64_t*)(srcH + (size_t)row2 * 2048 + c82 * 8),
                __ATOMIC_RELAXED, __HIP_MEMORY_SCOPE_AGENT);
          }
          if (++guard > 32) break;  // hang-proof bail
        }
      }
      #pragma unroll
      for (int i = 0; i < 16; ++i) {
        int ch = i * 512 + tid, row = ch >> 7, c8 = ch & 127;
        *(uint64_t*)(ldsH + row * 1024 + ((c8 * 8) ^ ((row & 7) << 4))) = tH[i];
      }
      __syncthreads();
      #pragma unroll
      for (int ks = 0; ks < 16; ++ks) {
        bf16x8 a = *(const bf16x8*)(
            ldsH + arow * 1024 + ((ks * 64 + lk * 16) ^ ((arow & 7) << 4)));
        acc[0] = __builtin_amdgcn_mfma_f32_16x16x32_bf16(a, bfrag[ks][0], acc[0], 0, 0, 0);
        acc[1] = __builtin_amdgcn_mfma_f32_16x16x32_bf16(a, bfrag[ks][1], acc[1], 0, 0, 0);
      }
      #pragma unroll
      for (int ni = 0; ni < 2; ++ni)
        #pragma unroll
        for (int r = 0; r < 4; ++r)
          gatesF[(wm * 16 + lk * 4 + r) * 68 + wn * 32 + ni * 16 + lr] = acc[ni][r];
      __syncthreads();
    }

    // cell update: 2 adjacent units (b=cb, u=2*cup, 2*cup+1)
    float h2v[2], c2v[2];
    #pragma unroll
    for (int it = 0; it < 2; ++it) {
      int u = cup * 2 + it;
      float gi = 0.f, gf = 0.f, gg = 0.f, go = 0.f;
      if (s > 0) {
        gi = gatesF[cb * 68 + u * 4 + 0];
        gf = gatesF[cb * 68 + u * 4 + 1];
        gg = gatesF[cb * 68 + u * 4 + 2];
        go = gatesF[cb * 68 + u * 4 + 3];
      }
      gi += bf2f(gv[it * 4 + 0]); gf += bf2f(gv[it * 4 + 1]);
      gg += bf2f(gv[it * 4 + 2]); go += bf2f(gv[it * 4 + 3]);
      float si = 1.f / (1.f + __expf(-gi));
      float sf = 1.f / (1.f + __expf(-gf));
      float so = 1.f / (1.f + __expf(-go));
      float tg = 1.f - 2.f / (1.f + __expf(2.f * gg));
      float c2 = sf * creg[it] + si * tg;
      float h2 = so * (1.f - 2.f / (1.f + __expf(2.f * c2)));
      h2 *= mreg; c2 *= mreg;
      creg[it] = c2; h2v[it] = h2; c2v[it] = c2;
    }
    // packed Y publish (one 4B sc1 store; the data IS the ready flag)
    {
      __hip_bfloat16 b0 = __float2bfloat16(h2v[0]);
      __hip_bfloat16 b1 = __float2bfloat16(h2v[1]);
      unsigned w = (unsigned)*(unsigned short*)&b0 |
                   ((unsigned)*(unsigned short*)&b1 << 16);
      uint32_t* yw = (uint32_t*)((char*)Y + ((size_t)t * 64 + cb) * 2048 +
                                 dir * 1024 + (bn * 16 + cup * 2) * 2);
      __hip_atomic_store(yw, w, __ATOMIC_RELAXED, __HIP_MEMORY_SCOPE_AGENT);
    }
    if (outH) {
      float2* ow = (float2*)(outH + ((size_t)t * 64 + cb) * 1024 +
                             dir * 512 + bn * 16 + cup * 2);
      *ow = make_float2(h2v[0], h2v[1]);
    }
    if (s == S_LEN - 1) {
      size_t fi = (size_t)cb * 1024 + dir * 512 + bn * 16 + cup * 2;
      hn[fi] = h2v[0]; hn[fi + 1] = h2v[1];
      cn[fi] = c2v[0]; cn[fi + 1] = c2v[1];
    }

    if (s < S_LEN - 1) {
      // pin program order: Y store issues before next-step prefetch/polls
      asm volatile("" ::: "memory");
      int tnx = dir ? (t - 1) : (t + 1);
      gv = *(const bf16x8*)(Gd + ((size_t)tnx * 64 + cb) * 2048 + bn * 64 + cup * 8);
      mreg = mask[tnx * 64 + cb];
    }
  }
}

// ---------- launcher ----------

extern "C" void kernel_launch(void* const* d_in, const int* in_sizes, int n_in,
                              void* d_out, int out_size, void* d_ws, size_t ws_size,
                              hipStream_t stream) {
  const float* x    = (const float*)d_in[0];
  const float* mask = (const float*)d_in[1];
  const float* Wih[4] = {(const float*)d_in[2], (const float*)d_in[6],
                         (const float*)d_in[10], (const float*)d_in[14]};
  const float* Whh[4] = {(const float*)d_in[3], (const float*)d_in[7],
                         (const float*)d_in[11], (const float*)d_in[15]};
  const float* bih[4] = {(const float*)d_in[4], (const float*)d_in[8],
                         (const float*)d_in[12], (const float*)d_in[16]};
  const float* bhh[4] = {(const float*)d_in[5], (const float*)d_in[9],
                         (const float*)d_in[13], (const float*)d_in[17]};

  char* ws = (char*)d_ws;
  __hip_bfloat16* Xbf   = (__hip_bfloat16*)(ws);                 // 32 MB
  __hip_bfloat16* Y0    = (__hip_bfloat16*)(ws + 33554432);      // 64 MB
  __hip_bfloat16* Y1    = (__hip_bfloat16*)(ws + 100663296);     // 64 MB
  __hip_bfloat16* WpIh0 = (__hip_bfloat16*)(ws + 167772160);     // 4 MB
  __hip_bfloat16* WpIh1 = (__hip_bfloat16*)(ws + 171966464);     // 8 MB
  __hip_bfloat16* WpHh  = (__hip_bfloat16*)(ws + 180355072);     // 8 MB
  float*          bsum  = (float*)(ws + 188743680);              // 32 KB
  __hip_bfloat16* Gbuf  = (__hip_bfloat16*)(ws + 188776448);     // 256 MB
  // total ws needed: ~457 MB

  float* out = (float*)d_out;
  float* hn = out + (size_t)S_LEN * BATCH * 1024;
  float* cn = hn + 2 * BATCH * 1024;

  // sentinel-fill the h-exchange buffers (0xFFFF bf16 = NaN, unreachable)
  hipMemsetAsync(Y0, 0xFF, (size_t)SB * 1024 * 2, stream);
  hipMemsetAsync(Y1, 0xFF, (size_t)SB * 1024 * 2, stream);

  // prep
  k_f32_to_bf16<<<8192, 256, 0, stream>>>(x, Xbf, SB * DDIM);
  for (int ld = 0; ld < 4; ld++) {
    int K = (ld < 2) ? 512 : 1024;
    __hip_bfloat16* dst = (ld < 2) ? (WpIh0 + (size_t)ld * 2048 * 512)
                                   : (WpIh1 + (size_t)(ld - 2) * 2048 * 1024);
    k_permW<<<(2048 * K) / 256, 256, 0, stream>>>(Wih[ld], dst, K);
    k_permW<<<(2048 * 512) / 256, 256, 0, stream>>>(Whh[ld], WpHh + (size_t)ld * 2048 * 512, 512);
    k_permB<<<8, 256, 0, stream>>>(bih[ld], bhh[ld], bsum + ld * 2048);
  }

  // layer 0
  k_gemm_in<<<dim3(256, 32), 256, 0, stream>>>(Xbf, WpIh0, bsum, Gbuf, 512);
  k_scan<<<64, 512, 0, stream>>>(Gbuf, WpHh, Y0, mask, nullptr, hn, cn);
  // layer 1
  k_gemm_in<<<dim3(256, 32), 256, 0, stream>>>(Y0, WpIh1, bsum + 2 * 2048, Gbuf, 1024);
  k_scan<<<64, 512, 0, stream>>>(Gbuf, WpHh + (size_t)2 * 2048 * 512, Y1, mask,
                                 out, hn + 2 * BATCH * 512, cn + 2 * BATCH * 512);
}